// Round 8
// baseline (206.606 us; speedup 1.0000x reference)
//
#include <hip/hip_runtime.h>

// Cayley map: R = ((1-s)I + 2A + 2 v v^T) / (1+s), s = |v|^2, A = skew(v)
// N = 4e6 points, fp32. Memory-bound: 48 MB read + 144 MB write -> ~30.5 us roofline.
// 4 points/thread => 3x float4 loads, 9x float4 stores (fully dense coverage).

__device__ __forceinline__ void cayley(float x, float y, float z, float* m) {
    float s   = x * x + y * y + z * z;
    float inv = 1.0f / (1.0f + s);
    float d   = 1.0f - s;
    m[0] = (d + 2.0f * x * x) * inv;
    m[1] = (2.0f * (x * y - z)) * inv;
    m[2] = (2.0f * (x * z + y)) * inv;
    m[3] = (2.0f * (x * y + z)) * inv;
    m[4] = (d + 2.0f * y * y) * inv;
    m[5] = (2.0f * (y * z - x)) * inv;
    m[6] = (2.0f * (x * z - y)) * inv;
    m[7] = (2.0f * (y * z + x)) * inv;
    m[8] = (d + 2.0f * z * z) * inv;
}

extern "C" __global__ __launch_bounds__(256)
void cayley_kernel(const float* __restrict__ t, float* __restrict__ out, int npts) {
    const int tid = blockIdx.x * 256 + threadIdx.x;
    const int p0  = tid * 4;
    if (p0 + 4 <= npts) {
        // 12 consecutive floats = points p0..p0+3
        const float4* in4 = (const float4*)t;
        float4 A = in4[tid * 3 + 0];
        float4 B = in4[tid * 3 + 1];
        float4 C = in4[tid * 3 + 2];
        float xs[4] = {A.x, A.w, B.z, C.y};
        float ys[4] = {A.y, B.x, B.w, C.z};
        float zs[4] = {A.z, B.y, C.x, C.w};
        float m[36];
        #pragma unroll
        for (int i = 0; i < 4; ++i)
            cayley(xs[i], ys[i], zs[i], &m[9 * i]);
        // 36 consecutive floats = 9 float4 stores
        float4* o4 = (float4*)out + (size_t)tid * 9;
        #pragma unroll
        for (int k = 0; k < 9; ++k)
            o4[k] = make_float4(m[4 * k + 0], m[4 * k + 1], m[4 * k + 2], m[4 * k + 3]);
    } else if (p0 < npts) {
        // tail (not hit for N=4e6, kept for generality)
        for (int p = p0; p < npts; ++p) {
            float mm[9];
            cayley(t[3 * p + 0], t[3 * p + 1], t[3 * p + 2], mm);
            for (int k = 0; k < 9; ++k) out[9 * p + k] = mm[k];
        }
    }
}

extern "C" void kernel_launch(void* const* d_in, const int* in_sizes, int n_in,
                              void* d_out, int out_size, void* d_ws, size_t ws_size,
                              hipStream_t stream) {
    const float* t = (const float*)d_in[0];
    float* out = (float*)d_out;
    const int npts = in_sizes[0] / 3;
    const int nthreads = (npts + 3) / 4;
    const int blocks = (nthreads + 255) / 256;
    cayley_kernel<<<blocks, 256, 0, stream>>>(t, out, npts);
}